// Round 1
// baseline (4674.583 us; speedup 1.0000x reference)
//
#include <hip/hip_runtime.h>

#define TILE 16
#define EPS 1e-5f

// Fused edge-decoder MLP, fp32 baseline (correctness anchor).
// One block (256 thr = 4 waves) processes TILE=16 edges end-to-end.
// GEMMs: thread j owns output column j; activations staged in LDS,
// weights streamed from L2 (384KB total, L2-resident).
__global__ __launch_bounds__(256) void edge_mlp(
    const float* __restrict__ x,
    const int* __restrict__ ei,
    const float* __restrict__ ln0_g, const float* __restrict__ ln0_b,
    const float* __restrict__ w1, const float* __restrict__ b1,
    const float* __restrict__ ln1_g, const float* __restrict__ ln1_b,
    const float* __restrict__ w2, const float* __restrict__ b2,
    const float* __restrict__ ln2_g, const float* __restrict__ ln2_b,
    const float* __restrict__ wp, const float* __restrict__ bp,
    const float* __restrict__ ww, const float* __restrict__ bw,
    float* __restrict__ out, int E)
{
    __shared__ __align__(16) float h0[TILE][256];  // 16KB: feats->LN0, later GEMM2 partial buf
    __shared__ __align__(16) float h1[TILE][256];  // 16KB: LN1+relu output
    __shared__ float red[TILE][4][2];              // per-wave reduction partials
    __shared__ float stat[TILE][2];                // mu, rstd per edge
    __shared__ int   sidx[TILE][2];

    const int tid  = threadIdx.x;
    const int lane = tid & 63;
    const int wv   = tid >> 6;
    const long base = (long)blockIdx.x * TILE;

    if (tid < TILE * 2) {
        const int e = tid >> 1, w = tid & 1;
        sidx[e][w] = (base + e < E) ? ei[(long)w * E + base + e] : 0;
    }
    __syncthreads();

    // ---------- Phase 1: gather + feats + LN0 -> h0 ----------
    const int jd   = tid & 127;    // feature dim within node vector
    const int half = tid >> 7;     // 0: s+d (cols 0..127), 1: s*d (cols 128..255)
    float v[TILE];
    #pragma unroll
    for (int e = 0; e < TILE; ++e) {
        const float s = x[(long)sidx[e][0] * 128 + jd];
        const float d = x[(long)sidx[e][1] * 128 + jd];
        v[e] = half ? s * d : s + d;
    }
    #pragma unroll
    for (int e = 0; e < TILE; ++e) {
        float s = v[e], q = v[e] * v[e];
        #pragma unroll
        for (int o = 32; o; o >>= 1) { s += __shfl_xor(s, o); q += __shfl_xor(q, o); }
        if (lane == 0) { red[e][wv][0] = s; red[e][wv][1] = q; }
    }
    __syncthreads();
    if (tid < TILE) {
        const float s  = red[tid][0][0] + red[tid][1][0] + red[tid][2][0] + red[tid][3][0];
        const float q  = red[tid][0][1] + red[tid][1][1] + red[tid][2][1] + red[tid][3][1];
        const float mu = s * (1.f / 256.f);
        const float var = q * (1.f / 256.f) - mu * mu;
        stat[tid][0] = mu;
        stat[tid][1] = rsqrtf(var + EPS);
    }
    __syncthreads();
    {
        const float g = ln0_g[tid], b = ln0_b[tid];
        #pragma unroll
        for (int e = 0; e < TILE; ++e)
            h0[e][tid] = (v[e] - stat[e][0]) * stat[e][1] * g + b;
    }
    __syncthreads();

    // ---------- Phase 2: GEMM1  c[e][j] = b1[j] + sum_k h0[e][k]*w1[k][j] ----------
    float acc[TILE];
    {
        const float bb = b1[tid];
        #pragma unroll
        for (int e = 0; e < TILE; ++e) acc[e] = bb;
        for (int k = 0; k < 256; k += 4) {
            const float wa = w1[(k + 0) * 256 + tid];
            const float wb = w1[(k + 1) * 256 + tid];
            const float wc = w1[(k + 2) * 256 + tid];
            const float wd = w1[(k + 3) * 256 + tid];
            #pragma unroll
            for (int e = 0; e < TILE; ++e) {
                const float4 h = *reinterpret_cast<const float4*>(&h0[e][k]);
                acc[e] = fmaf(h.x, wa, fmaf(h.y, wb, fmaf(h.z, wc, fmaf(h.w, wd, acc[e]))));
            }
        }
    }

    // ---------- Phase 3: LN1 + relu -> h1 ----------
    #pragma unroll
    for (int e = 0; e < TILE; ++e) {
        float s = acc[e], q = acc[e] * acc[e];
        #pragma unroll
        for (int o = 32; o; o >>= 1) { s += __shfl_xor(s, o); q += __shfl_xor(q, o); }
        if (lane == 0) { red[e][wv][0] = s; red[e][wv][1] = q; }
    }
    __syncthreads();
    if (tid < TILE) {
        const float s  = red[tid][0][0] + red[tid][1][0] + red[tid][2][0] + red[tid][3][0];
        const float q  = red[tid][0][1] + red[tid][1][1] + red[tid][2][1] + red[tid][3][1];
        const float mu = s * (1.f / 256.f);
        const float var = q * (1.f / 256.f) - mu * mu;
        stat[tid][0] = mu;
        stat[tid][1] = rsqrtf(var + EPS);
    }
    __syncthreads();
    {
        const float g = ln1_g[tid], b = ln1_b[tid];
        #pragma unroll
        for (int e = 0; e < TILE; ++e)
            h1[e][tid] = fmaxf((acc[e] - stat[e][0]) * stat[e][1] * g + b, 0.f);
    }
    __syncthreads();

    // ---------- Phase 4: GEMM2 (split-K over thread halves) ----------
    float acc2[TILE];
    {
        const int col = tid & 127;
        const int kh  = tid >> 7;          // 0: k in [0,128), 1: k in [128,256)
        const float bb = kh ? 0.f : b2[col];
        #pragma unroll
        for (int e = 0; e < TILE; ++e) acc2[e] = bb;
        const int k0 = kh * 128;
        for (int k = k0; k < k0 + 128; k += 4) {
            const float wa = w2[(k + 0) * 128 + col];
            const float wb = w2[(k + 1) * 128 + col];
            const float wc = w2[(k + 2) * 128 + col];
            const float wd = w2[(k + 3) * 128 + col];
            #pragma unroll
            for (int e = 0; e < TILE; ++e) {
                const float4 h = *reinterpret_cast<const float4*>(&h1[e][k]);
                acc2[e] = fmaf(h.x, wa, fmaf(h.y, wb, fmaf(h.z, wc, fmaf(h.w, wd, acc2[e]))));
            }
        }
        if (kh) {  // upper-half partials via LDS (reuse h0)
            #pragma unroll
            for (int e = 0; e < TILE; ++e) h0[e][col] = acc2[e];
        }
        __syncthreads();
        if (!kh) {
            #pragma unroll
            for (int e = 0; e < TILE; ++e) acc2[e] += h0[e][col];
        }
    }

    // ---------- Phase 5: LN2 stats (128 cols, waves 0-1) ----------
    if (tid < 128) {
        #pragma unroll
        for (int e = 0; e < TILE; ++e) {
            float s = acc2[e], q = acc2[e] * acc2[e];
            #pragma unroll
            for (int o = 32; o; o >>= 1) { s += __shfl_xor(s, o); q += __shfl_xor(q, o); }
            if (lane == 0) { red[e][wv][0] = s; red[e][wv][1] = q; }
        }
    }
    __syncthreads();
    if (tid < TILE) {
        const float s  = red[tid][0][0] + red[tid][1][0];
        const float q  = red[tid][0][1] + red[tid][1][1];
        const float mu = s * (1.f / 128.f);
        const float var = q * (1.f / 128.f) - mu * mu;
        stat[tid][0] = mu;
        stat[tid][1] = rsqrtf(var + EPS);
    }
    __syncthreads();

    // ---------- Phase 6: LN2+relu, heads, output ----------
    if (tid < 128) {
        const float g = ln2_g[tid], b = ln2_b[tid];
        const float wpv = wp[tid], wwv = ww[tid];
        #pragma unroll
        for (int e = 0; e < TILE; ++e) {
            const float t = fmaxf((acc2[e] - stat[e][0]) * stat[e][1] * g + b, 0.f);
            float p = t * wpv, w = t * wwv;
            #pragma unroll
            for (int o = 32; o; o >>= 1) { p += __shfl_xor(p, o); w += __shfl_xor(w, o); }
            if (lane == 0) { red[e][wv][0] = p; red[e][wv][1] = w; }
        }
    }
    __syncthreads();
    if (tid < TILE && base + tid < E) {
        const float p = red[tid][0][0] + red[tid][1][0] + bp[0];
        const float w = fmaxf(red[tid][0][1] + red[tid][1][1] + bw[0], 0.f);
        out[base + tid] = p;              // edge_probabilities (logits, no relu)
        out[(long)E + base + tid] = w;    // edge_weights (relu)
    }
}

extern "C" void kernel_launch(void* const* d_in, const int* in_sizes, int n_in,
                              void* d_out, int out_size, void* d_ws, size_t ws_size,
                              hipStream_t stream) {
    const float* x     = (const float*)d_in[0];
    const int*   ei    = (const int*)  d_in[1];
    const float* ln0_g = (const float*)d_in[2];
    const float* ln0_b = (const float*)d_in[3];
    const float* w1    = (const float*)d_in[4];
    const float* b1    = (const float*)d_in[5];
    const float* ln1_g = (const float*)d_in[6];
    const float* ln1_b = (const float*)d_in[7];
    const float* w2    = (const float*)d_in[8];
    const float* b2    = (const float*)d_in[9];
    const float* ln2_g = (const float*)d_in[10];
    const float* ln2_b = (const float*)d_in[11];
    const float* wp    = (const float*)d_in[12];
    const float* bp    = (const float*)d_in[13];
    const float* ww    = (const float*)d_in[14];
    const float* bw    = (const float*)d_in[15];

    const int E = in_sizes[1] / 2;
    const int grid = (E + TILE - 1) / TILE;
    edge_mlp<<<grid, 256, 0, stream>>>(x, ei, ln0_g, ln0_b, w1, b1, ln1_g, ln1_b,
                                       w2, b2, ln2_g, ln2_b, wp, bp, ww, bw,
                                       (float*)d_out, E);
}

// Round 7
// 1519.395 us; speedup vs baseline: 3.0766x; 3.0766x over previous
//
#include <hip/hip_runtime.h>

#define EPS 1e-5f

typedef __attribute__((ext_vector_type(8))) short s16x8;
typedef __attribute__((ext_vector_type(4))) short s16x4;
typedef __attribute__((ext_vector_type(2))) short s16x2;
typedef __attribute__((ext_vector_type(4))) float f32x4;

static __device__ __forceinline__ short f2bf(float x) {
    union { float f; unsigned u; } v; v.f = x;
    return (short)((v.u + 0x7fffu + ((v.u >> 16) & 1u)) >> 16);  // RNE
}
static __device__ __forceinline__ float bf2f(short h) {
    union { float f; unsigned u; } v; v.u = ((unsigned)(unsigned short)h) << 16;
    return v.f;
}
struct bfhl { short hi, lo; };
// exact split: x = hi + lo + r, |r| <= 2^-18 |x|; lo never denormal in bf16
static __device__ __forceinline__ bfhl splitbf(float x) {
    bfhl r; r.hi = f2bf(x); r.lo = f2bf(x - bf2f(r.hi)); return r;
}

// ---- prep: repack w1,w2 (fp32 [K][N]) into split-bf16 MFMA A-fragments of W^T ----
// A-frag for tile (ft,ks): lane l, elem j <- W[ks*32 + (l>>4)*8 + j][ft*16 + (l&15)]
__global__ __launch_bounds__(256) void prep_weights(
    const float* __restrict__ w1, const float* __restrict__ w2,
    short* __restrict__ wb1h, short* __restrict__ wb1l,
    short* __restrict__ wb2h, short* __restrict__ wb2l)
{
    const int t = blockIdx.x * 256 + threadIdx.x;
    const int lane = t & 63, frag = t >> 6;
    const int row0 = ((frag & 7) * 32) + ((lane >> 4) * 8);   // k base
    short hi[8], lo[8];
    if (frag < 128) {                 // w1: 16 ft x 8 ks
        const int col = (frag >> 3) * 16 + (lane & 15);
        #pragma unroll
        for (int j = 0; j < 8; ++j) {
            const bfhl r = splitbf(w1[(row0 + j) * 256 + col]);
            hi[j] = r.hi; lo[j] = r.lo;
        }
        *reinterpret_cast<s16x8*>(&wb1h[frag * 512 + lane * 8]) = *reinterpret_cast<s16x8*>(hi);
        *reinterpret_cast<s16x8*>(&wb1l[frag * 512 + lane * 8]) = *reinterpret_cast<s16x8*>(lo);
    } else if (frag < 192) {          // w2: 8 ft x 8 ks
        const int f = frag - 128;
        const int col = (f >> 3) * 16 + (lane & 15);
        #pragma unroll
        for (int j = 0; j < 8; ++j) {
            const bfhl r = splitbf(w2[(row0 + j) * 128 + col]);
            hi[j] = r.hi; lo[j] = r.lo;
        }
        *reinterpret_cast<s16x8*>(&wb2h[f * 512 + lane * 8]) = *reinterpret_cast<s16x8*>(hi);
        *reinterpret_cast<s16x8*>(&wb2l[f * 512 + lane * 8]) = *reinterpret_cast<s16x8*>(lo);
    }
}

// ---- fused MLP: 64 edges/block, 512 thr (8 waves), split-bf16 3-MFMA GEMMs ----
// DIAGNOSTIC CONFIG: no LDS swizzle, no h0/h1 aliasing (separate buffers).
// acc = Wh·Hl + Wl·Hh + Wh·Hh  (dropped Wl·Hl <= 2^-18 rel)
__global__ __launch_bounds__(512, 2) void edge_mlp(
    const float* __restrict__ x, const int* __restrict__ ei,
    const float* __restrict__ ln0_g, const float* __restrict__ ln0_b,
    const short* __restrict__ wb1h, const short* __restrict__ wb1l,
    const float* __restrict__ b1,
    const float* __restrict__ ln1_g, const float* __restrict__ ln1_b,
    const short* __restrict__ wb2h, const short* __restrict__ wb2l,
    const float* __restrict__ b2,
    const float* __restrict__ ln2_g, const float* __restrict__ ln2_b,
    const float* __restrict__ wp, const float* __restrict__ bp,
    const float* __restrict__ ww, const float* __restrict__ bw,
    float* __restrict__ out, int E)
{
    __shared__ __align__(16) short h0h[64 * 256];   // 32KB each
    __shared__ __align__(16) short h0l[64 * 256];
    __shared__ __align__(16) short h1h[64 * 256];
    __shared__ __align__(16) short h1l[64 * 256];
    __shared__ __align__(8) float red[8][64][2];
    __shared__ __align__(8) float stat[64][2];
    __shared__ int sidx[64][2];

    const int tid = threadIdx.x, lane = tid & 63, w = tid >> 6;
    const int g = lane >> 4, c15 = lane & 15;
    const long base = (long)blockIdx.x * 64;

    if (tid < 128) {
        const int e = tid >> 1, s = tid & 1;
        const long idx = base + e;
        sidx[e][s] = (idx < E) ? ei[(long)s * E + idx] : 0;
    }
    __syncthreads();

    // ---------- Phase 1: gather + feats + LN0 -> h0h/h0l ----------
    {
        const int c = 2 * lane;   // dims c,c+1 -> feat cols c,c+1 and 128+c,129+c
        const float ga = ln0_g[c], gb = ln0_g[c + 1], gc = ln0_g[128 + c], gd = ln0_g[129 + c];
        const float ba = ln0_b[c], bb = ln0_b[c + 1], bc = ln0_b[128 + c], bd = ln0_b[129 + c];
        char* hhc = (char*)h0h;
        char* hlc = (char*)h0l;
        #pragma unroll
        for (int e8 = 0; e8 < 8; ++e8) {
            const int e = w * 8 + e8;
            const float2 sv = *reinterpret_cast<const float2*>(&x[(long)sidx[e][0] * 128 + c]);
            const float2 dv = *reinterpret_cast<const float2*>(&x[(long)sidx[e][1] * 128 + c]);
            const float a0 = sv.x + dv.x, a1 = sv.y + dv.y;
            const float m0 = sv.x * dv.x, m1 = sv.y * dv.y;
            float s = a0 + a1 + m0 + m1;
            float q = a0 * a0 + a1 * a1 + m0 * m0 + m1 * m1;
            #pragma unroll
            for (int o = 32; o; o >>= 1) { s += __shfl_xor(s, o); q += __shfl_xor(q, o); }
            const float mu = s * (1.f / 256.f);
            const float rs = rsqrtf(q * (1.f / 256.f) - mu * mu + EPS);
            const bfhl r0 = splitbf((a0 - mu) * rs * ga + ba);
            const bfhl r1 = splitbf((a1 - mu) * rs * gb + bb);
            const bfhl r2 = splitbf((m0 - mu) * rs * gc + bc);
            const bfhl r3 = splitbf((m1 - mu) * rs * gd + bd);
            s16x2 p0h, p0l, p1h, p1l;
            p0h[0] = r0.hi; p0l[0] = r0.lo;
            p0h[1] = r1.hi; p0l[1] = r1.lo;
            p1h[0] = r2.hi; p1l[0] = r2.lo;
            p1h[1] = r3.hi; p1l[1] = r3.lo;
            const int o0 = e * 512 + 4 * lane;          // plain linear, no swizzle
            const int o1 = e * 512 + 256 + 4 * lane;
            *reinterpret_cast<s16x2*>(hhc + o0) = p0h;
            *reinterpret_cast<s16x2*>(hhc + o1) = p1h;
            *reinterpret_cast<s16x2*>(hlc + o0) = p0l;
            *reinterpret_cast<s16x2*>(hlc + o1) = p1l;
        }
    }
    __syncthreads();

    // ---------- Phase 2: GEMM1  D[feat 256][edge 64], wave owns feats [w*32,w*32+32) ----------
    f32x4 acc[2][4] = {};   // [mt][nt]
    {
        const char* hhc = (const char*)h0h;
        const char* hlc = (const char*)h0l;
        for (int ks = 0; ks < 8; ++ks) {
            const s16x8 a0h = *reinterpret_cast<const s16x8*>(&wb1h[((w * 2 + 0) * 8 + ks) * 512 + lane * 8]);
            const s16x8 a0l = *reinterpret_cast<const s16x8*>(&wb1l[((w * 2 + 0) * 8 + ks) * 512 + lane * 8]);
            const s16x8 a1h = *reinterpret_cast<const s16x8*>(&wb1h[((w * 2 + 1) * 8 + ks) * 512 + lane * 8]);
            const s16x8 a1l = *reinterpret_cast<const s16x8*>(&wb1l[((w * 2 + 1) * 8 + ks) * 512 + lane * 8]);
            const int kb = ks * 64 + g * 16;
            #pragma unroll
            for (int nt = 0; nt < 4; ++nt) {
                const int e = nt * 16 + c15;
                const int off = e * 512 + kb;
                const s16x8 bh = *reinterpret_cast<const s16x8*>(hhc + off);
                const s16x8 bl = *reinterpret_cast<const s16x8*>(hlc + off);
                acc[0][nt] = __builtin_amdgcn_mfma_f32_16x16x32_bf16(a0h, bl, acc[0][nt], 0, 0, 0);
                acc[0][nt] = __builtin_amdgcn_mfma_f32_16x16x32_bf16(a0l, bh, acc[0][nt], 0, 0, 0);
                acc[0][nt] = __builtin_amdgcn_mfma_f32_16x16x32_bf16(a0h, bh, acc[0][nt], 0, 0, 0);
                acc[1][nt] = __builtin_amdgcn_mfma_f32_16x16x32_bf16(a1h, bl, acc[1][nt], 0, 0, 0);
                acc[1][nt] = __builtin_amdgcn_mfma_f32_16x16x32_bf16(a1l, bh, acc[1][nt], 0, 0, 0);
                acc[1][nt] = __builtin_amdgcn_mfma_f32_16x16x32_bf16(a1h, bh, acc[1][nt], 0, 0, 0);
            }
        }
    }

    // ---------- Phase 3: bias + LN1 stats + apply + relu -> h1h/h1l ----------
    {
        float bi[2][4];
        *reinterpret_cast<float4*>(bi[0]) = *reinterpret_cast<const float4*>(&b1[w * 32 + g * 4]);
        *reinterpret_cast<float4*>(bi[1]) = *reinterpret_cast<const float4*>(&b1[w * 32 + 16 + g * 4]);
        float s[4], q[4];
        #pragma unroll
        for (int nt = 0; nt < 4; ++nt) { s[nt] = 0.f; q[nt] = 0.f; }
        #pragma unroll
        for (int mt = 0; mt < 2; ++mt)
            #pragma unroll
            for (int nt = 0; nt < 4; ++nt)
                #pragma unroll
                for (int r = 0; r < 4; ++r) {
                    const float v2 = acc[mt][nt][r] + bi[mt][r];
                    acc[mt][nt][r] = v2; s[nt] += v2; q[nt] += v2 * v2;
                }
        #pragma unroll
        for (int nt = 0; nt < 4; ++nt) {
            s[nt] += __shfl_xor(s[nt], 16); q[nt] += __shfl_xor(q[nt], 16);
            s[nt] += __shfl_xor(s[nt], 32); q[nt] += __shfl_xor(q[nt], 32);
        }
        const float sg = (g == 0) ? s[0] : (g == 1) ? s[1] : (g == 2) ? s[2] : s[3];
        const float qg = (g == 0) ? q[0] : (g == 1) ? q[1] : (g == 2) ? q[2] : q[3];
        red[w][lane][0] = sg; red[w][lane][1] = qg;   // lane == edge
    }
    __syncthreads();
    if (tid < 64) {
        float S = 0.f, Q = 0.f;
        #pragma unroll
        for (int w2 = 0; w2 < 8; ++w2) { S += red[w2][tid][0]; Q += red[w2][tid][1]; }
        const float mu = S * (1.f / 256.f);
        stat[tid][0] = mu;
        stat[tid][1] = rsqrtf(Q * (1.f / 256.f) - mu * mu + EPS);
    }
    __syncthreads();
    {
        float gv[2][4], bv[2][4];
        *reinterpret_cast<float4*>(gv[0]) = *reinterpret_cast<const float4*>(&ln1_g[w * 32 + g * 4]);
        *reinterpret_cast<float4*>(gv[1]) = *reinterpret_cast<const float4*>(&ln1_g[w * 32 + 16 + g * 4]);
        *reinterpret_cast<float4*>(bv[0]) = *reinterpret_cast<const float4*>(&ln1_b[w * 32 + g * 4]);
        *reinterpret_cast<float4*>(bv[1]) = *reinterpret_cast<const float4*>(&ln1_b[w * 32 + 16 + g * 4]);
        char* hhc = (char*)h1h;
        char* hlc = (char*)h1l;
        #pragma unroll
        for (int mt = 0; mt < 2; ++mt)
            #pragma unroll
            for (int nt = 0; nt < 4; ++nt) {
                const int e = nt * 16 + c15;
                const float2 st = *reinterpret_cast<const float2*>(stat[e]);
                s16x4 ph, pl;
                #pragma unroll
                for (int r = 0; r < 4; ++r) {
                    const bfhl rr = splitbf(fmaxf((acc[mt][nt][r] - st.x) * st.y * gv[mt][r] + bv[mt][r], 0.f));
                    ph[r] = rr.hi; pl[r] = rr.lo;
                }
                const int f0 = w * 32 + mt * 16 + g * 4;
                const int off = e * 512 + f0 * 2;       // plain linear
                *reinterpret_cast<s16x4*>(hhc + off) = ph;
                *reinterpret_cast<s16x4*>(hlc + off) = pl;
            }
    }
    __syncthreads();

    // ---------- Phase 4: GEMM2  D[feat 128][edge 64], wave owns feats [w*16,w*16+16) ----------
    f32x4 acc2[4] = {};
    {
        const char* hhc = (const char*)h1h;
        const char* hlc = (const char*)h1l;
        for (int ks = 0; ks < 8; ++ks) {
            const s16x8 ah = *reinterpret_cast<const s16x8*>(&wb2h[(w * 8 + ks) * 512 + lane * 8]);
            const s16x8 al = *reinterpret_cast<const s16x8*>(&wb2l[(w * 8 + ks) * 512 + lane * 8]);
            const int kb = ks * 64 + g * 16;
            #pragma unroll
            for (int nt = 0; nt < 4; ++nt) {
                const int e = nt * 16 + c15;
                const int off = e * 512 + kb;
                const s16x8 bh = *reinterpret_cast<const s16x8*>(hhc + off);
                const s16x8 bl = *reinterpret_cast<const s16x8*>(hlc + off);
                acc2[nt] = __builtin_amdgcn_mfma_f32_16x16x32_bf16(ah, bl, acc2[nt], 0, 0, 0);
                acc2[nt] = __builtin_amdgcn_mfma_f32_16x16x32_bf16(al, bh, acc2[nt], 0, 0, 0);
                acc2[nt] = __builtin_amdgcn_mfma_f32_16x16x32_bf16(ah, bh, acc2[nt], 0, 0, 0);
            }
        }
    }

    // ---------- Phase 5: bias + LN2 stats ----------
    {
        float bi[4];
        *reinterpret_cast<float4*>(bi) = *reinterpret_cast<const float4*>(&b2[w * 16 + g * 4]);
        float s[4], q[4];
        #pragma unroll
        for (int nt = 0; nt < 4; ++nt) {
            s[nt] = 0.f; q[nt] = 0.f;
            #pragma unroll
            for (int r = 0; r < 4; ++r) {
                const float v2 = acc2[nt][r] + bi[r];
                acc2[nt][r] = v2; s[nt] += v2; q[nt] += v2 * v2;
            }
        }
        #pragma unroll
        for (int nt = 0; nt < 4; ++nt) {
            s[nt] += __shfl_xor(s[nt], 16); q[nt] += __shfl_xor(q[nt], 16);
            s[nt] += __shfl_xor(s[nt], 32); q[nt] += __shfl_xor(q[nt], 32);
        }
        const float sg = (g == 0) ? s[0] : (g == 1) ? s[1] : (g == 2) ? s[2] : s[3];
        const float qg = (g == 0) ? q[0] : (g == 1) ? q[1] : (g == 2) ? q[2] : q[3];
        red[w][lane][0] = sg; red[w][lane][1] = qg;
    }
    __syncthreads();
    if (tid < 64) {
        float S = 0.f, Q = 0.f;
        #pragma unroll
        for (int w2 = 0; w2 < 8; ++w2) { S += red[w2][tid][0]; Q += red[w2][tid][1]; }
        const float mu = S * (1.f / 128.f);
        stat[tid][0] = mu;
        stat[tid][1] = rsqrtf(Q * (1.f / 128.f) - mu * mu + EPS);
    }
    __syncthreads();

    // ---------- Phase 6: LN2 apply + relu + heads ----------
    {
        float gv[4], bv[4], pv[4], wv[4];
        *reinterpret_cast<float4*>(gv) = *reinterpret_cast<const float4*>(&ln2_g[w * 16 + g * 4]);
        *reinterpret_cast<float4*>(bv) = *reinterpret_cast<const float4*>(&ln2_b[w * 16 + g * 4]);
        *reinterpret_cast<float4*>(pv) = *reinterpret_cast<const float4*>(&wp[w * 16 + g * 4]);
        *reinterpret_cast<float4*>(wv) = *reinterpret_cast<const float4*>(&ww[w * 16 + g * 4]);
        float pp[4], ws2[4];
        #pragma unroll
        for (int nt = 0; nt < 4; ++nt) {
            const int e = nt * 16 + c15;
            const float2 st = *reinterpret_cast<const float2*>(stat[e]);
            pp[nt] = 0.f; ws2[nt] = 0.f;
            #pragma unroll
            for (int r = 0; r < 4; ++r) {
                const float t = fmaxf((acc2[nt][r] - st.x) * st.y * gv[r] + bv[r], 0.f);
                pp[nt] += t * pv[r]; ws2[nt] += t * wv[r];
            }
        }
        #pragma unroll
        for (int nt = 0; nt < 4; ++nt) {
            pp[nt] += __shfl_xor(pp[nt], 16); ws2[nt] += __shfl_xor(ws2[nt], 16);
            pp[nt] += __shfl_xor(pp[nt], 32); ws2[nt] += __shfl_xor(ws2[nt], 32);
        }
        const float pg = (g == 0) ? pp[0] : (g == 1) ? pp[1] : (g == 2) ? pp[2] : pp[3];
        const float wg = (g == 0) ? ws2[0] : (g == 1) ? ws2[1] : (g == 2) ? ws2[2] : ws2[3];
        red[w][lane][0] = pg; red[w][lane][1] = wg;
    }
    __syncthreads();
    if (tid < 64 && base + tid < E) {
        float P = bp[0], W = bw[0];
        #pragma unroll
        for (int w2 = 0; w2 < 8; ++w2) { P += red[w2][tid][0]; W += red[w2][tid][1]; }
        out[base + tid] = P;                         // logits
        out[(long)E + base + tid] = fmaxf(W, 0.f);   // relu'd weights
    }
}

extern "C" void kernel_launch(void* const* d_in, const int* in_sizes, int n_in,
                              void* d_out, int out_size, void* d_ws, size_t ws_size,
                              hipStream_t stream) {
    const float* x     = (const float*)d_in[0];
    const int*   ei    = (const int*)  d_in[1];
    const float* ln0_g = (const float*)d_in[2];
    const float* ln0_b = (const float*)d_in[3];
    const float* w1    = (const float*)d_in[4];
    const float* b1    = (const float*)d_in[5];
    const float* ln1_g = (const float*)d_in[6];
    const float* ln1_b = (const float*)d_in[7];
    const float* w2    = (const float*)d_in[8];
    const float* b2    = (const float*)d_in[9];
    const float* ln2_g = (const float*)d_in[10];
    const float* ln2_b = (const float*)d_in[11];
    const float* wp    = (const float*)d_in[12];
    const float* bp    = (const float*)d_in[13];
    const float* ww    = (const float*)d_in[14];
    const float* bw    = (const float*)d_in[15];

    short* wb1h = (short*)d_ws;             // 128 frags * 512
    short* wb1l = wb1h + 128 * 512;
    short* wb2h = wb1l + 128 * 512;         // 64 frags * 512
    short* wb2l = wb2h + 64 * 512;          // total 384KB

    const int E = in_sizes[1] / 2;
    prep_weights<<<48, 256, 0, stream>>>(w1, w2, wb1h, wb1l, wb2h, wb2l);
    edge_mlp<<<(E + 63) / 64, 512, 0, stream>>>(x, ei, ln0_g, ln0_b, wb1h, wb1l, b1,
                                                ln1_g, ln1_b, wb2h, wb2l, b2, ln2_g, ln2_b,
                                                wp, bp, ww, bw, (float*)d_out, E);
}

// Round 9
// 887.313 us; speedup vs baseline: 5.2682x; 1.7124x over previous
//
#include <hip/hip_runtime.h>

#define EPS 1e-5f
#define PITCH 528   // bytes per LDS row (264 bf16); 132 words % 32 banks = 4 -> 2-way max

typedef __attribute__((ext_vector_type(8))) short s16x8;
typedef __attribute__((ext_vector_type(4))) short s16x4;
typedef __attribute__((ext_vector_type(2))) short s16x2;
typedef __attribute__((ext_vector_type(4))) float f32x4;

static __device__ __forceinline__ short f2bf(float x) {
    union { float f; unsigned u; } v; v.f = x;
    return (short)((v.u + 0x7fffu + ((v.u >> 16) & 1u)) >> 16);  // RNE
}
static __device__ __forceinline__ float bf2f(short h) {
    union { float f; unsigned u; } v; v.u = ((unsigned)(unsigned short)h) << 16;
    return v.f;
}
struct bfhl { short hi, lo; };
// exact split: x = hi + lo + r, |r| <= 2^-17 |x|; bf16 lo never denormal
static __device__ __forceinline__ bfhl splitbf(float x) {
    bfhl r; r.hi = f2bf(x); r.lo = f2bf(x - bf2f(r.hi)); return r;
}

// ---- prep: repack w1,w2 (fp32 [K][N]) into split-bf16 MFMA A-fragments of W^T ----
// A-frag for tile (ft,ks): lane l, elem j <- W[ks*32 + (l>>4)*8 + j][ft*16 + (l&15)]
__global__ __launch_bounds__(256) void prep_weights(
    const float* __restrict__ w1, const float* __restrict__ w2,
    short* __restrict__ wb1h, short* __restrict__ wb1l,
    short* __restrict__ wb2h, short* __restrict__ wb2l)
{
    const int t = blockIdx.x * 256 + threadIdx.x;
    const int lane = t & 63, frag = t >> 6;
    const int row0 = ((frag & 7) * 32) + ((lane >> 4) * 8);   // k base
    short hi[8], lo[8];
    if (frag < 128) {                 // w1: 16 ft x 8 ks
        const int col = (frag >> 3) * 16 + (lane & 15);
        #pragma unroll
        for (int j = 0; j < 8; ++j) {
            const bfhl r = splitbf(w1[(row0 + j) * 256 + col]);
            hi[j] = r.hi; lo[j] = r.lo;
        }
        *reinterpret_cast<s16x8*>(&wb1h[frag * 512 + lane * 8]) = *reinterpret_cast<s16x8*>(hi);
        *reinterpret_cast<s16x8*>(&wb1l[frag * 512 + lane * 8]) = *reinterpret_cast<s16x8*>(lo);
    } else if (frag < 192) {          // w2: 8 ft x 8 ks
        const int f = frag - 128;
        const int col = (f >> 3) * 16 + (lane & 15);
        #pragma unroll
        for (int j = 0; j < 8; ++j) {
            const bfhl r = splitbf(w2[(row0 + j) * 128 + col]);
            hi[j] = r.hi; lo[j] = r.lo;
        }
        *reinterpret_cast<s16x8*>(&wb2h[f * 512 + lane * 8]) = *reinterpret_cast<s16x8*>(hi);
        *reinterpret_cast<s16x8*>(&wb2l[f * 512 + lane * 8]) = *reinterpret_cast<s16x8*>(lo);
    }
}

// ---- fused MLP: 64 edges/block, 512 thr (8 waves), split-bf16 3-MFMA GEMMs ----
// acc = Wh·Hl + Wl·Hh + Wh·Hh  (dropped Wl·Hl <= 2^-17 rel)
// LDS: linear rows with PITCH=528B padding (bank-conflict-free); NO swizzle,
// NO h0/h1 aliasing (separate buffers) -- only delta vs passing R7 is the pitch.
__global__ __launch_bounds__(512, 2) void edge_mlp(
    const float* __restrict__ x, const int* __restrict__ ei,
    const float* __restrict__ ln0_g, const float* __restrict__ ln0_b,
    const short* __restrict__ wb1h, const short* __restrict__ wb1l,
    const float* __restrict__ b1,
    const float* __restrict__ ln1_g, const float* __restrict__ ln1_b,
    const short* __restrict__ wb2h, const short* __restrict__ wb2l,
    const float* __restrict__ b2,
    const float* __restrict__ ln2_g, const float* __restrict__ ln2_b,
    const float* __restrict__ wp, const float* __restrict__ bp,
    const float* __restrict__ ww, const float* __restrict__ bw,
    float* __restrict__ out, int E)
{
    __shared__ __align__(16) short h0h[64 * 264];   // 33KB each (264 = PITCH/2)
    __shared__ __align__(16) short h0l[64 * 264];
    __shared__ __align__(16) short h1h[64 * 264];
    __shared__ __align__(16) short h1l[64 * 264];
    __shared__ __align__(8) float red[8][64][2];
    __shared__ __align__(8) float stat[64][2];
    __shared__ int sidx[64][2];

    const int tid = threadIdx.x, lane = tid & 63, w = tid >> 6;
    const int g = lane >> 4, c15 = lane & 15;
    const long base = (long)blockIdx.x * 64;

    if (tid < 128) {
        const int e = tid >> 1, s = tid & 1;
        const long idx = base + e;
        sidx[e][s] = (idx < E) ? ei[(long)s * E + idx] : 0;
    }
    __syncthreads();

    // ---------- Phase 1: gather + feats + LN0 -> h0h/h0l ----------
    {
        const int c = 2 * lane;   // dims c,c+1 -> feat cols c,c+1 and 128+c,129+c
        const float ga = ln0_g[c], gb = ln0_g[c + 1], gc = ln0_g[128 + c], gd = ln0_g[129 + c];
        const float ba = ln0_b[c], bb = ln0_b[c + 1], bc = ln0_b[128 + c], bd = ln0_b[129 + c];
        char* hhc = (char*)h0h;
        char* hlc = (char*)h0l;
        #pragma unroll
        for (int e8 = 0; e8 < 8; ++e8) {
            const int e = w * 8 + e8;
            const float2 sv = *reinterpret_cast<const float2*>(&x[(long)sidx[e][0] * 128 + c]);
            const float2 dv = *reinterpret_cast<const float2*>(&x[(long)sidx[e][1] * 128 + c]);
            const float a0 = sv.x + dv.x, a1 = sv.y + dv.y;
            const float m0 = sv.x * dv.x, m1 = sv.y * dv.y;
            float s = a0 + a1 + m0 + m1;
            float q = a0 * a0 + a1 * a1 + m0 * m0 + m1 * m1;
            #pragma unroll
            for (int o = 32; o; o >>= 1) { s += __shfl_xor(s, o); q += __shfl_xor(q, o); }
            const float mu = s * (1.f / 256.f);
            const float rs = rsqrtf(q * (1.f / 256.f) - mu * mu + EPS);
            const bfhl r0 = splitbf((a0 - mu) * rs * ga + ba);
            const bfhl r1 = splitbf((a1 - mu) * rs * gb + bb);
            const bfhl r2 = splitbf((m0 - mu) * rs * gc + bc);
            const bfhl r3 = splitbf((m1 - mu) * rs * gd + bd);
            s16x2 p0h, p0l, p1h, p1l;
            p0h[0] = r0.hi; p0l[0] = r0.lo;
            p0h[1] = r1.hi; p0l[1] = r1.lo;
            p1h[0] = r2.hi; p1l[0] = r2.lo;
            p1h[1] = r3.hi; p1l[1] = r3.lo;
            const int o0 = e * PITCH + 4 * lane;
            const int o1 = e * PITCH + 256 + 4 * lane;
            *reinterpret_cast<s16x2*>(hhc + o0) = p0h;
            *reinterpret_cast<s16x2*>(hhc + o1) = p1h;
            *reinterpret_cast<s16x2*>(hlc + o0) = p0l;
            *reinterpret_cast<s16x2*>(hlc + o1) = p1l;
        }
    }
    __syncthreads();

    // ---------- Phase 2: GEMM1  D[feat 256][edge 64], wave owns feats [w*32,w*32+32) ----------
    f32x4 acc[2][4] = {};   // [mt][nt]
    {
        const char* hhc = (const char*)h0h;
        const char* hlc = (const char*)h0l;
        for (int ks = 0; ks < 8; ++ks) {
            const s16x8 a0h = *reinterpret_cast<const s16x8*>(&wb1h[((w * 2 + 0) * 8 + ks) * 512 + lane * 8]);
            const s16x8 a0l = *reinterpret_cast<const s16x8*>(&wb1l[((w * 2 + 0) * 8 + ks) * 512 + lane * 8]);
            const s16x8 a1h = *reinterpret_cast<const s16x8*>(&wb1h[((w * 2 + 1) * 8 + ks) * 512 + lane * 8]);
            const s16x8 a1l = *reinterpret_cast<const s16x8*>(&wb1l[((w * 2 + 1) * 8 + ks) * 512 + lane * 8]);
            const int kb = ks * 64 + g * 16;
            #pragma unroll
            for (int nt = 0; nt < 4; ++nt) {
                const int e = nt * 16 + c15;
                const int off = e * PITCH + kb;
                const s16x8 bh = *reinterpret_cast<const s16x8*>(hhc + off);
                const s16x8 bl = *reinterpret_cast<const s16x8*>(hlc + off);
                acc[0][nt] = __builtin_amdgcn_mfma_f32_16x16x32_bf16(a0h, bl, acc[0][nt], 0, 0, 0);
                acc[0][nt] = __builtin_amdgcn_mfma_f32_16x16x32_bf16(a0l, bh, acc[0][nt], 0, 0, 0);
                acc[0][nt] = __builtin_amdgcn_mfma_f32_16x16x32_bf16(a0h, bh, acc[0][nt], 0, 0, 0);
                acc[1][nt] = __builtin_amdgcn_mfma_f32_16x16x32_bf16(a1h, bl, acc[1][nt], 0, 0, 0);
                acc[1][nt] = __builtin_amdgcn_mfma_f32_16x16x32_bf16(a1l, bh, acc[1][nt], 0, 0, 0);
                acc[1][nt] = __builtin_amdgcn_mfma_f32_16x16x32_bf16(a1h, bh, acc[1][nt], 0, 0, 0);
            }
        }
    }

    // ---------- Phase 3: bias + LN1 stats + apply + relu -> h1h/h1l ----------
    {
        float bi[2][4];
        *reinterpret_cast<float4*>(bi[0]) = *reinterpret_cast<const float4*>(&b1[w * 32 + g * 4]);
        *reinterpret_cast<float4*>(bi[1]) = *reinterpret_cast<const float4*>(&b1[w * 32 + 16 + g * 4]);
        float s[4], q[4];
        #pragma unroll
        for (int nt = 0; nt < 4; ++nt) { s[nt] = 0.f; q[nt] = 0.f; }
        #pragma unroll
        for (int mt = 0; mt < 2; ++mt)
            #pragma unroll
            for (int nt = 0; nt < 4; ++nt)
                #pragma unroll
                for (int r = 0; r < 4; ++r) {
                    const float v2 = acc[mt][nt][r] + bi[mt][r];
                    acc[mt][nt][r] = v2; s[nt] += v2; q[nt] += v2 * v2;
                }
        #pragma unroll
        for (int nt = 0; nt < 4; ++nt) {
            s[nt] += __shfl_xor(s[nt], 16); q[nt] += __shfl_xor(q[nt], 16);
            s[nt] += __shfl_xor(s[nt], 32); q[nt] += __shfl_xor(q[nt], 32);
        }
        const float sg = (g == 0) ? s[0] : (g == 1) ? s[1] : (g == 2) ? s[2] : s[3];
        const float qg = (g == 0) ? q[0] : (g == 1) ? q[1] : (g == 2) ? q[2] : q[3];
        red[w][lane][0] = sg; red[w][lane][1] = qg;   // lane == edge
    }
    __syncthreads();
    if (tid < 64) {
        float S = 0.f, Q = 0.f;
        #pragma unroll
        for (int w2 = 0; w2 < 8; ++w2) { S += red[w2][tid][0]; Q += red[w2][tid][1]; }
        const float mu = S * (1.f / 256.f);
        stat[tid][0] = mu;
        stat[tid][1] = rsqrtf(Q * (1.f / 256.f) - mu * mu + EPS);
    }
    __syncthreads();
    {
        float gv[2][4], bv[2][4];
        *reinterpret_cast<float4*>(gv[0]) = *reinterpret_cast<const float4*>(&ln1_g[w * 32 + g * 4]);
        *reinterpret_cast<float4*>(gv[1]) = *reinterpret_cast<const float4*>(&ln1_g[w * 32 + 16 + g * 4]);
        *reinterpret_cast<float4*>(bv[0]) = *reinterpret_cast<const float4*>(&ln1_b[w * 32 + g * 4]);
        *reinterpret_cast<float4*>(bv[1]) = *reinterpret_cast<const float4*>(&ln1_b[w * 32 + 16 + g * 4]);
        char* hhc = (char*)h1h;
        char* hlc = (char*)h1l;
        #pragma unroll
        for (int mt = 0; mt < 2; ++mt)
            #pragma unroll
            for (int nt = 0; nt < 4; ++nt) {
                const int e = nt * 16 + c15;
                const float2 st = *reinterpret_cast<const float2*>(stat[e]);
                s16x4 ph, pl;
                #pragma unroll
                for (int r = 0; r < 4; ++r) {
                    const bfhl rr = splitbf(fmaxf((acc[mt][nt][r] - st.x) * st.y * gv[mt][r] + bv[mt][r], 0.f));
                    ph[r] = rr.hi; pl[r] = rr.lo;
                }
                const int f0 = w * 32 + mt * 16 + g * 4;
                const int off = e * PITCH + f0 * 2;
                *reinterpret_cast<s16x4*>(hhc + off) = ph;
                *reinterpret_cast<s16x4*>(hlc + off) = pl;
            }
    }
    __syncthreads();

    // ---------- Phase 4: GEMM2  D[feat 128][edge 64], wave owns feats [w*16,w*16+16) ----------
    f32x4 acc2[4] = {};
    {
        const char* hhc = (const char*)h1h;
        const char* hlc = (const char*)h1l;
        for (int ks = 0; ks < 8; ++ks) {
            const s16x8 ah = *reinterpret_cast<const s16x8*>(&wb2h[(w * 8 + ks) * 512 + lane * 8]);
            const s16x8 al = *reinterpret_cast<const s16x8*>(&wb2l[(w * 8 + ks) * 512 + lane * 8]);
            const int kb = ks * 64 + g * 16;
            #pragma unroll
            for (int nt = 0; nt < 4; ++nt) {
                const int e = nt * 16 + c15;
                const int off = e * PITCH + kb;
                const s16x8 bh = *reinterpret_cast<const s16x8*>(hhc + off);
                const s16x8 bl = *reinterpret_cast<const s16x8*>(hlc + off);
                acc2[nt] = __builtin_amdgcn_mfma_f32_16x16x32_bf16(ah, bl, acc2[nt], 0, 0, 0);
                acc2[nt] = __builtin_amdgcn_mfma_f32_16x16x32_bf16(al, bh, acc2[nt], 0, 0, 0);
                acc2[nt] = __builtin_amdgcn_mfma_f32_16x16x32_bf16(ah, bh, acc2[nt], 0, 0, 0);
            }
        }
    }

    // ---------- Phase 5: bias + LN2 stats ----------
    {
        float bi[4];
        *reinterpret_cast<float4*>(bi) = *reinterpret_cast<const float4*>(&b2[w * 16 + g * 4]);
        float s[4], q[4];
        #pragma unroll
        for (int nt = 0; nt < 4; ++nt) {
            s[nt] = 0.f; q[nt] = 0.f;
            #pragma unroll
            for (int r = 0; r < 4; ++r) {
                const float v2 = acc2[nt][r] + bi[r];
                acc2[nt][r] = v2; s[nt] += v2; q[nt] += v2 * v2;
            }
        }
        #pragma unroll
        for (int nt = 0; nt < 4; ++nt) {
            s[nt] += __shfl_xor(s[nt], 16); q[nt] += __shfl_xor(q[nt], 16);
            s[nt] += __shfl_xor(s[nt], 32); q[nt] += __shfl_xor(q[nt], 32);
        }
        const float sg = (g == 0) ? s[0] : (g == 1) ? s[1] : (g == 2) ? s[2] : s[3];
        const float qg = (g == 0) ? q[0] : (g == 1) ? q[1] : (g == 2) ? q[2] : q[3];
        red[w][lane][0] = sg; red[w][lane][1] = qg;
    }
    __syncthreads();
    if (tid < 64) {
        float S = 0.f, Q = 0.f;
        #pragma unroll
        for (int w2 = 0; w2 < 8; ++w2) { S += red[w2][tid][0]; Q += red[w2][tid][1]; }
        const float mu = S * (1.f / 128.f);
        stat[tid][0] = mu;
        stat[tid][1] = rsqrtf(Q * (1.f / 128.f) - mu * mu + EPS);
    }
    __syncthreads();

    // ---------- Phase 6: LN2 apply + relu + heads ----------
    {
        float gv[4], bv[4], pv[4], wv[4];
        *reinterpret_cast<float4*>(gv) = *reinterpret_cast<const float4*>(&ln2_g[w * 16 + g * 4]);
        *reinterpret_cast<float4*>(bv) = *reinterpret_cast<const float4*>(&ln2_b[w * 16 + g * 4]);
        *reinterpret_cast<float4*>(pv) = *reinterpret_cast<const float4*>(&wp[w * 16 + g * 4]);
        *reinterpret_cast<float4*>(wv) = *reinterpret_cast<const float4*>(&ww[w * 16 + g * 4]);
        float pp[4], ws2[4];
        #pragma unroll
        for (int nt = 0; nt < 4; ++nt) {
            const int e = nt * 16 + c15;
            const float2 st = *reinterpret_cast<const float2*>(stat[e]);
            pp[nt] = 0.f; ws2[nt] = 0.f;
            #pragma unroll
            for (int r = 0; r < 4; ++r) {
                const float t = fmaxf((acc2[nt][r] - st.x) * st.y * gv[r] + bv[r], 0.f);
                pp[nt] += t * pv[r]; ws2[nt] += t * wv[r];
            }
        }
        #pragma unroll
        for (int nt = 0; nt < 4; ++nt) {
            pp[nt] += __shfl_xor(pp[nt], 16); ws2[nt] += __shfl_xor(ws2[nt], 16);
            pp[nt] += __shfl_xor(pp[nt], 32); ws2[nt] += __shfl_xor(ws2[nt], 32);
        }
        const float pg = (g == 0) ? pp[0] : (g == 1) ? pp[1] : (g == 2) ? pp[2] : pp[3];
        const float wg = (g == 0) ? ws2[0] : (g == 1) ? ws2[1] : (g == 2) ? ws2[2] : ws2[3];
        red[w][lane][0] = pg; red[w][lane][1] = wg;
    }
    __syncthreads();
    if (tid < 64 && base + tid < E) {
        float P = bp[0], W = bw[0];
        #pragma unroll
        for (int w2 = 0; w2 < 8; ++w2) { P += red[w2][tid][0]; W += red[w2][tid][1]; }
        out[base + tid] = P;                         // logits
        out[(long)E + base + tid] = fmaxf(W, 0.f);   // relu'd weights
    }
}

extern "C" void kernel_launch(void* const* d_in, const int* in_sizes, int n_in,
                              void* d_out, int out_size, void* d_ws, size_t ws_size,
                              hipStream_t stream) {
    const float* x     = (const float*)d_in[0];
    const int*   ei    = (const int*)  d_in[1];
    const float* ln0_g = (const float*)d_in[2];
    const float* ln0_b = (const float*)d_in[3];
    const float* w1    = (const float*)d_in[4];
    const float* b1    = (const float*)d_in[5];
    const float* ln1_g = (const float*)d_in[6];
    const float* ln1_b = (const float*)d_in[7];
    const float* w2    = (const float*)d_in[8];
    const float* b2    = (const float*)d_in[9];
    const float* ln2_g = (const float*)d_in[10];
    const float* ln2_b = (const float*)d_in[11];
    const float* wp    = (const float*)d_in[12];
    const float* bp    = (const float*)d_in[13];
    const float* ww    = (const float*)d_in[14];
    const float* bw    = (const float*)d_in[15];

    short* wb1h = (short*)d_ws;             // 128 frags * 512
    short* wb1l = wb1h + 128 * 512;
    short* wb2h = wb1l + 128 * 512;         // 64 frags * 512
    short* wb2l = wb2h + 64 * 512;          // total 384KB

    const int E = in_sizes[1] / 2;
    prep_weights<<<48, 256, 0, stream>>>(w1, w2, wb1h, wb1l, wb2h, wb2l);
    edge_mlp<<<(E + 63) / 64, 512, 0, stream>>>(x, ei, ln0_g, ln0_b, wb1h, wb1l, b1,
                                                ln1_g, ln1_b, wb2h, wb2l, b2, ln2_g, ln2_b,
                                                wp, bp, ww, bw, (float*)d_out, E);
}

// Round 13
// 867.069 us; speedup vs baseline: 5.3912x; 1.0233x over previous
//
#include <hip/hip_runtime.h>

#define EPS 1e-5f
#define PITCH 528   // bytes per LDS row (264 bf16); 132 words % 32 banks = 4

typedef __attribute__((ext_vector_type(8))) short s16x8;
typedef __attribute__((ext_vector_type(4))) short s16x4;
typedef __attribute__((ext_vector_type(2))) short s16x2;
typedef __attribute__((ext_vector_type(4))) float f32x4;

static __device__ __forceinline__ short f2bf(float x) {
    union { float f; unsigned u; } v; v.f = x;
    return (short)((v.u + 0x7fffu + ((v.u >> 16) & 1u)) >> 16);  // RNE
}
static __device__ __forceinline__ float bf2f(short h) {
    union { float f; unsigned u; } v; v.u = ((unsigned)(unsigned short)h) << 16;
    return v.f;
}
struct bfhl { short hi, lo; };
// exact split: x = hi + lo + r, |r| <= 2^-17 |x|; bf16 lo never denormal
static __device__ __forceinline__ bfhl splitbf(float x) {
    bfhl r; r.hi = f2bf(x); r.lo = f2bf(x - bf2f(r.hi)); return r;
}

// ---- prep: repack w1,w2 (fp32 [K][N]) into split-bf16 MFMA A-fragments of W^T ----
// A-frag for tile (ft,ks): lane l, elem j <- W[ks*32 + (l>>4)*8 + j][ft*16 + (l&15)]
__global__ __launch_bounds__(256) void prep_weights(
    const float* __restrict__ w1, const float* __restrict__ w2,
    short* __restrict__ wb1h, short* __restrict__ wb1l,
    short* __restrict__ wb2h, short* __restrict__ wb2l)
{
    const int t = blockIdx.x * 256 + threadIdx.x;
    const int lane = t & 63, frag = t >> 6;
    const int row0 = ((frag & 7) * 32) + ((lane >> 4) * 8);   // k base
    short hi[8], lo[8];
    if (frag < 128) {                 // w1: 16 ft x 8 ks
        const int col = (frag >> 3) * 16 + (lane & 15);
        #pragma unroll
        for (int j = 0; j < 8; ++j) {
            const bfhl r = splitbf(w1[(row0 + j) * 256 + col]);
            hi[j] = r.hi; lo[j] = r.lo;
        }
        *reinterpret_cast<s16x8*>(&wb1h[frag * 512 + lane * 8]) = *reinterpret_cast<s16x8*>(hi);
        *reinterpret_cast<s16x8*>(&wb1l[frag * 512 + lane * 8]) = *reinterpret_cast<s16x8*>(lo);
    } else if (frag < 192) {          // w2: 8 ft x 8 ks
        const int f = frag - 128;
        const int col = (f >> 3) * 16 + (lane & 15);
        #pragma unroll
        for (int j = 0; j < 8; ++j) {
            const bfhl r = splitbf(w2[(row0 + j) * 128 + col]);
            hi[j] = r.hi; lo[j] = r.lo;
        }
        *reinterpret_cast<s16x8*>(&wb2h[f * 512 + lane * 8]) = *reinterpret_cast<s16x8*>(hi);
        *reinterpret_cast<s16x8*>(&wb2l[f * 512 + lane * 8]) = *reinterpret_cast<s16x8*>(lo);
    }
}

// ---- fused MLP: 64 edges/block, 1024 thr (16 waves), split-bf16 3-MFMA GEMMs ----
// acc = Wh·Hl + Wl·Hh + Wh·Hh  (dropped Wl·Hl <= 2^-17 rel)
// HARD CONSTRAINT (empirical, R2-R12): LDS must stay > 80KB so only ONE block
// is resident per CU. Every 2-blocks/CU build failed at ~0.04 absmax
// regardless of numerics; every 1-block/CU build passed at 0.0039.
// TLP comes from 16 waves in the single block (4 waves/SIMD).
__global__ __launch_bounds__(1024, 4) void edge_mlp(
    const float* __restrict__ x, const int* __restrict__ ei,
    const float* __restrict__ ln0_g, const float* __restrict__ ln0_b,
    const short* __restrict__ wb1h, const short* __restrict__ wb1l,
    const float* __restrict__ b1,
    const float* __restrict__ ln1_g, const float* __restrict__ ln1_b,
    const short* __restrict__ wb2h, const short* __restrict__ wb2l,
    const float* __restrict__ b2,
    const float* __restrict__ ln2_g, const float* __restrict__ ln2_b,
    const float* __restrict__ wp, const float* __restrict__ bp,
    const float* __restrict__ ww, const float* __restrict__ bw,
    float* __restrict__ out, int E)
{
    __shared__ __align__(16) short h0h[64 * 264];   // 33.8KB each; total ~141KB
    __shared__ __align__(16) short h0l[64 * 264];
    __shared__ __align__(16) short h1h[64 * 264];
    __shared__ __align__(16) short h1l[64 * 264];
    __shared__ __align__(8) float red[16][64][2];
    __shared__ __align__(8) float stat[64][2];
    __shared__ int sidx[64][2];

    const int tid = threadIdx.x, lane = tid & 63, w = tid >> 6;   // w in 0..15
    const int g = lane >> 4, c15 = lane & 15;
    const long base = (long)blockIdx.x * 64;

    if (tid < 128) {
        const int e = tid >> 1, s = tid & 1;
        const long idx = base + e;
        sidx[e][s] = (idx < E) ? ei[(long)s * E + idx] : 0;
    }
    __syncthreads();

    // ---------- Phase 1: gather + feats + LN0 -> h0h/h0l (wave w: edges w*4..w*4+3) ----------
    {
        const int c = 2 * lane;   // dims c,c+1 -> feat cols c,c+1 and 128+c,129+c
        const float ga = ln0_g[c], gb = ln0_g[c + 1], gc = ln0_g[128 + c], gd = ln0_g[129 + c];
        const float ba = ln0_b[c], bb = ln0_b[c + 1], bc = ln0_b[128 + c], bd = ln0_b[129 + c];
        char* hhc = (char*)h0h;
        char* hlc = (char*)h0l;
        #pragma unroll
        for (int e8 = 0; e8 < 4; ++e8) {
            const int e = w * 4 + e8;
            const float2 sv = *reinterpret_cast<const float2*>(&x[(long)sidx[e][0] * 128 + c]);
            const float2 dv = *reinterpret_cast<const float2*>(&x[(long)sidx[e][1] * 128 + c]);
            const float a0 = sv.x + dv.x, a1 = sv.y + dv.y;
            const float m0 = sv.x * dv.x, m1 = sv.y * dv.y;
            float s = a0 + a1 + m0 + m1;
            float q = a0 * a0 + a1 * a1 + m0 * m0 + m1 * m1;
            #pragma unroll
            for (int o = 32; o; o >>= 1) { s += __shfl_xor(s, o); q += __shfl_xor(q, o); }
            const float mu = s * (1.f / 256.f);
            const float rs = rsqrtf(q * (1.f / 256.f) - mu * mu + EPS);
            const bfhl r0 = splitbf((a0 - mu) * rs * ga + ba);
            const bfhl r1 = splitbf((a1 - mu) * rs * gb + bb);
            const bfhl r2 = splitbf((m0 - mu) * rs * gc + bc);
            const bfhl r3 = splitbf((m1 - mu) * rs * gd + bd);
            s16x2 p0h, p0l, p1h, p1l;
            p0h[0] = r0.hi; p0l[0] = r0.lo;
            p0h[1] = r1.hi; p0l[1] = r1.lo;
            p1h[0] = r2.hi; p1l[0] = r2.lo;
            p1h[1] = r3.hi; p1l[1] = r3.lo;
            const int o0 = e * PITCH + 4 * lane;
            const int o1 = e * PITCH + 256 + 4 * lane;
            *reinterpret_cast<s16x2*>(hhc + o0) = p0h;
            *reinterpret_cast<s16x2*>(hhc + o1) = p1h;
            *reinterpret_cast<s16x2*>(hlc + o0) = p0l;
            *reinterpret_cast<s16x2*>(hlc + o1) = p1l;
        }
    }
    __syncthreads();

    // ---------- Phase 2: GEMM1  D[feat 256][edge 64], wave owns feats [w*16,w*16+16) ----------
    f32x4 acc[4] = {};   // [nt]
    {
        const char* hhc = (const char*)h0h;
        const char* hlc = (const char*)h0l;
        for (int ks = 0; ks < 8; ++ks) {
            const s16x8 ah = *reinterpret_cast<const s16x8*>(&wb1h[(w * 8 + ks) * 512 + lane * 8]);
            const s16x8 al = *reinterpret_cast<const s16x8*>(&wb1l[(w * 8 + ks) * 512 + lane * 8]);
            const int kb = ks * 64 + g * 16;
            #pragma unroll
            for (int nt = 0; nt < 4; ++nt) {
                const int e = nt * 16 + c15;
                const int off = e * PITCH + kb;
                const s16x8 bh = *reinterpret_cast<const s16x8*>(hhc + off);
                const s16x8 bl = *reinterpret_cast<const s16x8*>(hlc + off);
                acc[nt] = __builtin_amdgcn_mfma_f32_16x16x32_bf16(ah, bl, acc[nt], 0, 0, 0);
                acc[nt] = __builtin_amdgcn_mfma_f32_16x16x32_bf16(al, bh, acc[nt], 0, 0, 0);
                acc[nt] = __builtin_amdgcn_mfma_f32_16x16x32_bf16(ah, bh, acc[nt], 0, 0, 0);
            }
        }
    }

    // ---------- Phase 3: bias + LN1 stats + apply + relu -> h1h/h1l ----------
    {
        float bi[4];
        *reinterpret_cast<float4*>(bi) = *reinterpret_cast<const float4*>(&b1[w * 16 + g * 4]);
        float s[4], q[4];
        #pragma unroll
        for (int nt = 0; nt < 4; ++nt) {
            s[nt] = 0.f; q[nt] = 0.f;
            #pragma unroll
            for (int r = 0; r < 4; ++r) {
                const float v2 = acc[nt][r] + bi[r];
                acc[nt][r] = v2; s[nt] += v2; q[nt] += v2 * v2;
            }
        }
        #pragma unroll
        for (int nt = 0; nt < 4; ++nt) {
            s[nt] += __shfl_xor(s[nt], 16); q[nt] += __shfl_xor(q[nt], 16);
            s[nt] += __shfl_xor(s[nt], 32); q[nt] += __shfl_xor(q[nt], 32);
        }
        const float sg = (g == 0) ? s[0] : (g == 1) ? s[1] : (g == 2) ? s[2] : s[3];
        const float qg = (g == 0) ? q[0] : (g == 1) ? q[1] : (g == 2) ? q[2] : q[3];
        red[w][lane][0] = sg; red[w][lane][1] = qg;   // lane == edge for nt=g
    }
    __syncthreads();
    if (tid < 64) {
        float S = 0.f, Q = 0.f;
        #pragma unroll
        for (int w2 = 0; w2 < 16; ++w2) { S += red[w2][tid][0]; Q += red[w2][tid][1]; }
        const float mu = S * (1.f / 256.f);
        stat[tid][0] = mu;
        stat[tid][1] = rsqrtf(Q * (1.f / 256.f) - mu * mu + EPS);
    }
    __syncthreads();
    {
        float gv[4], bv[4];
        *reinterpret_cast<float4*>(gv) = *reinterpret_cast<const float4*>(&ln1_g[w * 16 + g * 4]);
        *reinterpret_cast<float4*>(bv) = *reinterpret_cast<const float4*>(&ln1_b[w * 16 + g * 4]);
        char* hhc = (char*)h1h;
        char* hlc = (char*)h1l;
        #pragma unroll
        for (int nt = 0; nt < 4; ++nt) {
            const int e = nt * 16 + c15;
            const float2 st = *reinterpret_cast<const float2*>(stat[e]);
            s16x4 ph, pl;
            #pragma unroll
            for (int r = 0; r < 4; ++r) {
                const bfhl rr = splitbf(fmaxf((acc[nt][r] - st.x) * st.y * gv[r] + bv[r], 0.f));
                ph[r] = rr.hi; pl[r] = rr.lo;
            }
            const int off = e * PITCH + (w * 16 + g * 4) * 2;
            *reinterpret_cast<s16x4*>(hhc + off) = ph;
            *reinterpret_cast<s16x4*>(hlc + off) = pl;
        }
    }
    __syncthreads();

    // ---------- Phase 4: GEMM2  D[feat 128][edge 64] ----------
    // wave w: feat tile ft2 = w>>1, edge-half h = w&1 (nt = 2h, 2h+1)
    const int ft2 = w >> 1, hf = w & 1;
    f32x4 acc2[2] = {};
    {
        const char* hhc = (const char*)h1h;
        const char* hlc = (const char*)h1l;
        for (int ks = 0; ks < 8; ++ks) {
            const s16x8 ah = *reinterpret_cast<const s16x8*>(&wb2h[(ft2 * 8 + ks) * 512 + lane * 8]);
            const s16x8 al = *reinterpret_cast<const s16x8*>(&wb2l[(ft2 * 8 + ks) * 512 + lane * 8]);
            const int kb = ks * 64 + g * 16;
            #pragma unroll
            for (int ntl = 0; ntl < 2; ++ntl) {
                const int e = (2 * hf + ntl) * 16 + c15;
                const int off = e * PITCH + kb;
                const s16x8 bh = *reinterpret_cast<const s16x8*>(hhc + off);
                const s16x8 bl = *reinterpret_cast<const s16x8*>(hlc + off);
                acc2[ntl] = __builtin_amdgcn_mfma_f32_16x16x32_bf16(ah, bl, acc2[ntl], 0, 0, 0);
                acc2[ntl] = __builtin_amdgcn_mfma_f32_16x16x32_bf16(al, bh, acc2[ntl], 0, 0, 0);
                acc2[ntl] = __builtin_amdgcn_mfma_f32_16x16x32_bf16(ah, bh, acc2[ntl], 0, 0, 0);
            }
        }
    }

    // ---------- Phase 5: bias + LN2 stats ----------
    {
        float bi[4];
        *reinterpret_cast<float4*>(bi) = *reinterpret_cast<const float4*>(&b2[ft2 * 16 + g * 4]);
        float s[2], q[2];
        #pragma unroll
        for (int ntl = 0; ntl < 2; ++ntl) {
            s[ntl] = 0.f; q[ntl] = 0.f;
            #pragma unroll
            for (int r = 0; r < 4; ++r) {
                const float v2 = acc2[ntl][r] + bi[r];
                acc2[ntl][r] = v2; s[ntl] += v2; q[ntl] += v2 * v2;
            }
        }
        #pragma unroll
        for (int ntl = 0; ntl < 2; ++ntl) {
            s[ntl] += __shfl_xor(s[ntl], 16); q[ntl] += __shfl_xor(q[ntl], 16);
            s[ntl] += __shfl_xor(s[ntl], 32); q[ntl] += __shfl_xor(q[ntl], 32);
        }
        if ((g >> 1) == hf) {   // lane == edge for nt = g (global), ntl = g&1
            red[w][lane][0] = (g & 1) ? s[1] : s[0];
            red[w][lane][1] = (g & 1) ? q[1] : q[0];
        }
    }
    __syncthreads();
    if (tid < 64) {
        const int hE = tid >> 5;   // which edge-half this edge lives in
        float S = 0.f, Q = 0.f;
        #pragma unroll
        for (int w2 = hE; w2 < 16; w2 += 2) { S += red[w2][tid][0]; Q += red[w2][tid][1]; }
        const float mu = S * (1.f / 128.f);
        stat[tid][0] = mu;
        stat[tid][1] = rsqrtf(Q * (1.f / 128.f) - mu * mu + EPS);
    }
    __syncthreads();

    // ---------- Phase 6: LN2 apply + relu + heads ----------
    {
        float gv[4], bv[4], pv[4], wv[4];
        *reinterpret_cast<float4*>(gv) = *reinterpret_cast<const float4*>(&ln2_g[ft2 * 16 + g * 4]);
        *reinterpret_cast<float4*>(bv) = *reinterpret_cast<const float4*>(&ln2_b[ft2 * 16 + g * 4]);
        *reinterpret_cast<float4*>(pv) = *reinterpret_cast<const float4*>(&wp[ft2 * 16 + g * 4]);
        *reinterpret_cast<float4*>(wv) = *reinterpret_cast<const float4*>(&ww[ft2 * 16 + g * 4]);
        float pp[2], ws2[2];
        #pragma unroll
        for (int ntl = 0; ntl < 2; ++ntl) {
            const int e = (2 * hf + ntl) * 16 + c15;
            const float2 st = *reinterpret_cast<const float2*>(stat[e]);
            pp[ntl] = 0.f; ws2[ntl] = 0.f;
            #pragma unroll
            for (int r = 0; r < 4; ++r) {
                const float t = fmaxf((acc2[ntl][r] - st.x) * st.y * gv[r] + bv[r], 0.f);
                pp[ntl] += t * pv[r]; ws2[ntl] += t * wv[r];
            }
        }
        #pragma unroll
        for (int ntl = 0; ntl < 2; ++ntl) {
            pp[ntl] += __shfl_xor(pp[ntl], 16); ws2[ntl] += __shfl_xor(ws2[ntl], 16);
            pp[ntl] += __shfl_xor(pp[ntl], 32); ws2[ntl] += __shfl_xor(ws2[ntl], 32);
        }
        if ((g >> 1) == hf) {
            red[w][lane][0] = (g & 1) ? pp[1] : pp[0];
            red[w][lane][1] = (g & 1) ? ws2[1] : ws2[0];
        }
    }
    __syncthreads();
    if (tid < 64 && base + tid < E) {
        const int hE = tid >> 5;
        float P = bp[0], W = bw[0];
        #pragma unroll
        for (int w2 = hE; w2 < 16; w2 += 2) { P += red[w2][tid][0]; W += red[w2][tid][1]; }
        out[base + tid] = P;                         // logits
        out[(long)E + base + tid] = fmaxf(W, 0.f);   // relu'd weights
    }
}

extern "C" void kernel_launch(void* const* d_in, const int* in_sizes, int n_in,
                              void* d_out, int out_size, void* d_ws, size_t ws_size,
                              hipStream_t stream) {
    const float* x     = (const float*)d_in[0];
    const int*   ei    = (const int*)  d_in[1];
    const float* ln0_g = (const float*)d_in[2];
    const float* ln0_b = (const float*)d_in[3];
    const float* w1    = (const float*)d_in[4];
    const float* b1    = (const float*)d_in[5];
    const float* ln1_g = (const float*)d_in[6];
    const float* ln1_b = (const float*)d_in[7];
    const float* w2    = (const float*)d_in[8];
    const float* b2    = (const float*)d_in[9];
    const float* ln2_g = (const float*)d_in[10];
    const float* ln2_b = (const float*)d_in[11];
    const float* wp    = (const float*)d_in[12];
    const float* bp    = (const float*)d_in[13];
    const float* ww    = (const float*)d_in[14];
    const float* bw    = (const float*)d_in[15];

    short* wb1h = (short*)d_ws;             // 128 frags * 512
    short* wb1l = wb1h + 128 * 512;
    short* wb2h = wb1l + 128 * 512;         // 64 frags * 512
    short* wb2l = wb2h + 64 * 512;          // total 384KB

    const int E = in_sizes[1] / 2;
    prep_weights<<<48, 256, 0, stream>>>(w1, w2, wb1h, wb1l, wb2h, wb2l);
    edge_mlp<<<(E + 63) / 64, 1024, 0, stream>>>(x, ei, ln0_g, ln0_b, wb1h, wb1l, b1,
                                                 ln1_g, ln1_b, wb2h, wb2l, b2, ln2_g, ln2_b,
                                                 wp, bp, ww, bw, (float*)d_out, E);
}